// Round 1
// baseline (998.163 us; speedup 1.0000x reference)
//
#include <hip/hip_runtime.h>

// ---------------------------------------------------------------------------
// PolarGate forward: 2-layer signed GNN + MLP head.
//   agg1   : mean-aggregate x over pos/neg edges (atomics) + counts
//   layer1 : z1 = tanh([ [ap,x]@Wp1+bp1 , [an,x]@Wn1+bn1 ])      (into d_out z region)
//   agg2   : aggregate xp/xn over pos/neg edges (col-swizzled packing)
//   layer2 : z = tanh(tanh([hp2,hn2])@Ww+bw); MLP -> prob (fused)
// ---------------------------------------------------------------------------

__global__ __launch_bounds__(256) void pg_agg1(
    const float* __restrict__ x, const int* __restrict__ ei,
    float* __restrict__ psum, float* __restrict__ nsum,
    float* __restrict__ pcnt, float* __restrict__ ncnt, int E)
{
    int e = blockIdx.x * 4 + (threadIdx.x >> 6);
    if (e >= E) return;
    int lane = threadIdx.x & 63;
    int s  = ei[3 * e + 0];
    int d  = ei[3 * e + 1];
    int sg = ei[3 * e + 2];
    float v = x[(size_t)s * 64 + lane];
    if (sg > 0) {
        atomicAdd(psum + (size_t)d * 64 + lane, v);
        if (lane == 0) atomicAdd(pcnt + d, 1.0f);
    } else {
        atomicAdd(nsum + (size_t)d * 64 + lane, v);
        if (lane == 0) atomicAdd(ncnt + d, 1.0f);
    }
}

// layer-2 aggregation. Packing (per dst row, 64 cols):
//   psum cols 0..31  = sum of xp over POS edges   (A1)
//   psum cols 32..63 = sum of xn over POS edges   (B1)
//   nsum cols 0..31  = sum of xn over NEG edges   (A2)  <- lane^32
//   nsum cols 32..63 = sum of xp over NEG edges   (B2)  <- lane^32
__global__ __launch_bounds__(256) void pg_agg2(
    const float* __restrict__ z1, const int* __restrict__ ei,
    float* __restrict__ psum, float* __restrict__ nsum, int E)
{
    int e = blockIdx.x * 4 + (threadIdx.x >> 6);
    if (e >= E) return;
    int lane = threadIdx.x & 63;
    int s  = ei[3 * e + 0];
    int d  = ei[3 * e + 1];
    int sg = ei[3 * e + 2];
    float v = z1[(size_t)s * 64 + lane];
    if (sg > 0) {
        atomicAdd(psum + (size_t)d * 64 + lane, v);
    } else {
        atomicAdd(nsum + (size_t)d * 64 + (lane ^ 32), v);
    }
}

// One wave per node; 4 waves/block; each block handles 32 nodes (8 iters).
__global__ __launch_bounds__(256) void pg_layer1(
    const float* __restrict__ x,
    const float* __restrict__ psum, const float* __restrict__ nsum,
    const float* __restrict__ pcnt, const float* __restrict__ ncnt,
    const float* __restrict__ Wp, const float* __restrict__ bp,
    const float* __restrict__ Wn, const float* __restrict__ bn,
    float* __restrict__ z1, int N)
{
    __shared__ float sWp[128 * 32];
    __shared__ float sWn[128 * 32];
    __shared__ float sB[64];
    __shared__ float sIn[4][2][128];   // [wave][p/n][k]

    int tid = threadIdx.x;
    for (int idx = tid; idx < 128 * 32; idx += 256) {
        sWp[idx] = Wp[idx];
        sWn[idx] = Wn[idx];
    }
    if (tid < 64) sB[tid] = (tid < 32) ? bp[tid] : bn[tid - 32];
    __syncthreads();

    int w = tid >> 6, lane = tid & 63, j = lane & 31;
    int half = (lane < 32) ? 0 : 1;
    const float* W = half ? sWn : sWp;

    for (int it = 0; it < 8; ++it) {
        int i = blockIdx.x * 32 + it * 4 + w;
        bool ok = (i < N);
        if (ok) {
            size_t base = (size_t)i * 64;
            float cp = fmaxf(pcnt[i], 1.0f);
            float cn = fmaxf(ncnt[i], 1.0f);
            float pv = psum[base + lane] / cp;
            float nv = nsum[base + lane] / cn;
            float xv = x[base + lane];
            sIn[w][0][lane]      = pv;
            sIn[w][0][64 + lane] = xv;
            sIn[w][1][lane]      = nv;
            sIn[w][1][64 + lane] = xv;
        }
        __syncthreads();
        if (ok) {
            const float* in = sIn[w][half];
            float a0 = 0.f, a1 = 0.f, a2 = 0.f, a3 = 0.f;
            #pragma unroll
            for (int k = 0; k < 128; k += 4) {
                a0 = fmaf(in[k + 0], W[(k + 0) * 32 + j], a0);
                a1 = fmaf(in[k + 1], W[(k + 1) * 32 + j], a1);
                a2 = fmaf(in[k + 2], W[(k + 2) * 32 + j], a2);
                a3 = fmaf(in[k + 3], W[(k + 3) * 32 + j], a3);
            }
            float acc = sB[lane] + ((a0 + a1) + (a2 + a3));
            z1[(size_t)i * 64 + lane] = tanhf(acc);
        }
        __syncthreads();
    }
}

// Fused: layer2 (96->32 x2) -> tanh -> @Ww -> tanh (=> z out) -> MLP head (=> prob)
// NOTE: zin aliases out (z region) deliberately; do NOT mark them restrict.
__global__ __launch_bounds__(256) void pg_layer2(
    const float* zin,
    const float* __restrict__ psum, const float* __restrict__ nsum,
    const float* __restrict__ pcnt, const float* __restrict__ ncnt,
    const float* __restrict__ Wp2, const float* __restrict__ bp2,
    const float* __restrict__ Wn2, const float* __restrict__ bn2,
    const float* __restrict__ Ww,  const float* __restrict__ bw,
    const float* __restrict__ Wm1, const float* __restrict__ bm1,
    const float* __restrict__ g1,  const float* __restrict__ be1,
    const float* __restrict__ rm1, const float* __restrict__ rv1,
    const float* __restrict__ Wm2, const float* __restrict__ bm2,
    const float* __restrict__ g2,  const float* __restrict__ be2,
    const float* __restrict__ rm2, const float* __restrict__ rv2,
    const float* __restrict__ Wm3, const float* __restrict__ bm3,
    float* out, int N)
{
    __shared__ float sWp2[96 * 32];
    __shared__ float sWn2[96 * 32];
    __shared__ float sWw[64 * 64];
    __shared__ float sWm1[64 * 64];
    __shared__ float sWm2[64 * 64];
    __shared__ float sWm3[64];
    __shared__ float sB2[64];
    __shared__ float sBw[64];
    __shared__ float sSc1[64], sOff1[64];
    __shared__ float sSc2[64], sOff2[64];
    __shared__ float sIn[4][2][96];
    __shared__ float sV[4][64];

    int tid = threadIdx.x;
    for (int idx = tid; idx < 96 * 32; idx += 256) {
        sWp2[idx] = Wp2[idx];
        sWn2[idx] = Wn2[idx];
    }
    for (int idx = tid; idx < 64 * 64; idx += 256) {
        sWw[idx]  = Ww[idx];
        sWm1[idx] = Wm1[idx];
        sWm2[idx] = Wm2[idx];
    }
    if (tid < 64) {
        sWm3[tid] = Wm3[tid];
        sB2[tid]  = (tid < 32) ? bp2[tid] : bn2[tid - 32];
        sBw[tid]  = bw[tid];
        float sc1 = g1[tid] * rsqrtf(rv1[tid] + 1e-5f);
        sSc1[tid]  = sc1;
        sOff1[tid] = (bm1[tid] - rm1[tid]) * sc1 + be1[tid];
        float sc2 = g2[tid] * rsqrtf(rv2[tid] + 1e-5f);
        sSc2[tid]  = sc2;
        sOff2[tid] = (bm2[tid] - rm2[tid]) * sc2 + be2[tid];
    }
    float b3 = bm3[0];
    __syncthreads();

    int w = tid >> 6, lane = tid & 63, j = lane & 31;
    int half = (lane < 32) ? 0 : 1;
    const float* W2 = half ? sWn2 : sWp2;

    for (int it = 0; it < 8; ++it) {
        int i = blockIdx.x * 32 + it * 4 + w;
        bool ok = (i < N);
        size_t base = (size_t)i * 64;
        if (ok) {
            float cp = fmaxf(pcnt[i], 1.0f);
            float cn = fmaxf(ncnt[i], 1.0f);
            float pv = psum[base + lane] / cp;   // l<32: A1, l>=32: B1
            float nv = nsum[base + lane] / cn;   // l<32: A2, l>=32: B2
            float zv = zin[base + lane];         // l<32: xp, l>=32: xn
            float* dst = sIn[w][half];
            dst[j]      = pv;
            dst[32 + j] = nv;
            dst[64 + j] = zv;
        }
        __syncthreads();
        float v = 0.f;
        if (ok) {
            const float* in = sIn[w][half];
            float a0 = 0.f, a1 = 0.f, a2 = 0.f, a3 = 0.f;
            #pragma unroll
            for (int k = 0; k < 96; k += 4) {
                a0 = fmaf(in[k + 0], W2[(k + 0) * 32 + j], a0);
                a1 = fmaf(in[k + 1], W2[(k + 1) * 32 + j], a1);
                a2 = fmaf(in[k + 2], W2[(k + 2) * 32 + j], a2);
                a3 = fmaf(in[k + 3], W2[(k + 3) * 32 + j], a3);
            }
            v = tanhf(sB2[lane] + ((a0 + a1) + (a2 + a3)));
            sV[w][lane] = v;
        }
        __syncthreads();
        if (ok) {
            const float* vv = sV[w];
            float a0 = 0.f, a1 = 0.f, a2 = 0.f, a3 = 0.f;
            #pragma unroll
            for (int k = 0; k < 64; k += 4) {
                a0 = fmaf(vv[k + 0], sWw[(k + 0) * 64 + lane], a0);
                a1 = fmaf(vv[k + 1], sWw[(k + 1) * 64 + lane], a1);
                a2 = fmaf(vv[k + 2], sWw[(k + 2) * 64 + lane], a2);
                a3 = fmaf(vv[k + 3], sWw[(k + 3) * 64 + lane], a3);
            }
            v = tanhf(sBw[lane] + ((a0 + a1) + (a2 + a3)));
            out[base + lane] = v;               // final z
        }
        __syncthreads();
        if (ok) sV[w][lane] = v;                // z for MLP
        __syncthreads();
        if (ok) {
            const float* vv = sV[w];
            float a0 = 0.f, a1 = 0.f, a2 = 0.f, a3 = 0.f;
            #pragma unroll
            for (int k = 0; k < 64; k += 4) {
                a0 = fmaf(vv[k + 0], sWm1[(k + 0) * 64 + lane], a0);
                a1 = fmaf(vv[k + 1], sWm1[(k + 1) * 64 + lane], a1);
                a2 = fmaf(vv[k + 2], sWm1[(k + 2) * 64 + lane], a2);
                a3 = fmaf(vv[k + 3], sWm1[(k + 3) * 64 + lane], a3);
            }
            float acc = (a0 + a1) + (a2 + a3);
            v = fmaxf(acc * sSc1[lane] + sOff1[lane], 0.f);   // h1
        }
        __syncthreads();
        if (ok) sV[w][lane] = v;                // h1 for Wm2
        __syncthreads();
        if (ok) {
            const float* vv = sV[w];
            float a0 = 0.f, a1 = 0.f, a2 = 0.f, a3 = 0.f;
            #pragma unroll
            for (int k = 0; k < 64; k += 4) {
                a0 = fmaf(vv[k + 0], sWm2[(k + 0) * 64 + lane], a0);
                a1 = fmaf(vv[k + 1], sWm2[(k + 1) * 64 + lane], a1);
                a2 = fmaf(vv[k + 2], sWm2[(k + 2) * 64 + lane], a2);
                a3 = fmaf(vv[k + 3], sWm2[(k + 3) * 64 + lane], a3);
            }
            float acc = (a0 + a1) + (a2 + a3);
            float h2 = fmaxf(acc * sSc2[lane] + sOff2[lane], 0.f);
            float t = h2 * sWm3[lane];
            #pragma unroll
            for (int off = 32; off > 0; off >>= 1) t += __shfl_down(t, off, 64);
            if (lane == 0) {
                out[(size_t)N * 64 + i] = 1.0f / (1.0f + expf(-(t + b3)));
            }
        }
        __syncthreads();
    }
}

extern "C" void kernel_launch(void* const* d_in, const int* in_sizes, int n_in,
                              void* d_out, int out_size, void* d_ws, size_t ws_size,
                              hipStream_t stream) {
    const float* x   = (const float*)d_in[0];
    const int*   ei  = (const int*)  d_in[1];
    const float* Wp1 = (const float*)d_in[2];
    const float* bp1 = (const float*)d_in[3];
    const float* Wn1 = (const float*)d_in[4];
    const float* bn1 = (const float*)d_in[5];
    const float* Wp2 = (const float*)d_in[6];
    const float* bp2 = (const float*)d_in[7];
    const float* Wn2 = (const float*)d_in[8];
    const float* bn2 = (const float*)d_in[9];
    const float* Ww  = (const float*)d_in[10];
    const float* bw  = (const float*)d_in[11];
    const float* Wm1 = (const float*)d_in[12];
    const float* bm1 = (const float*)d_in[13];
    const float* g1  = (const float*)d_in[14];
    const float* be1 = (const float*)d_in[15];
    const float* rm1 = (const float*)d_in[16];
    const float* rv1 = (const float*)d_in[17];
    const float* Wm2 = (const float*)d_in[18];
    const float* bm2 = (const float*)d_in[19];
    const float* g2  = (const float*)d_in[20];
    const float* be2 = (const float*)d_in[21];
    const float* rm2 = (const float*)d_in[22];
    const float* rv2 = (const float*)d_in[23];
    const float* Wm3 = (const float*)d_in[24];
    const float* bm3 = (const float*)d_in[25];
    float* out = (float*)d_out;

    int N = in_sizes[0] / 64;
    int E = in_sizes[1] / 3;

    float* psum = (float*)d_ws;
    float* nsum = psum + (size_t)N * 64;
    float* pcnt = nsum + (size_t)N * 64;
    float* ncnt = pcnt + N;
    float* z1   = out;   // stage z1 in d_out's z region; layer2 overwrites it

    // zero sums + counts
    hipMemsetAsync(d_ws, 0, (size_t)N * 130 * sizeof(float), stream);

    int eblocks = (E + 3) / 4;
    pg_agg1<<<eblocks, 256, 0, stream>>>(x, ei, psum, nsum, pcnt, ncnt, E);

    int nblocks = (N + 31) / 32;
    pg_layer1<<<nblocks, 256, 0, stream>>>(x, psum, nsum, pcnt, ncnt,
                                           Wp1, bp1, Wn1, bn1, z1, N);

    // zero sums only (keep counts)
    hipMemsetAsync(d_ws, 0, (size_t)N * 128 * sizeof(float), stream);

    pg_agg2<<<eblocks, 256, 0, stream>>>(z1, ei, psum, nsum, E);

    pg_layer2<<<nblocks, 256, 0, stream>>>(z1, psum, nsum, pcnt, ncnt,
                                           Wp2, bp2, Wn2, bn2, Ww, bw,
                                           Wm1, bm1, g1, be1, rm1, rv1,
                                           Wm2, bm2, g2, be2, rm2, rv2,
                                           Wm3, bm3, out, N);
}